// Round 10
// baseline (350.107 us; speedup 1.0000x reference)
//
#include <hip/hip_runtime.h>

typedef __bf16 bf16;
typedef __attribute__((ext_vector_type(8))) __bf16 bf16x8;
typedef __attribute__((ext_vector_type(4))) float f32x4;

union U16x8 { uint4 u; bf16 h[8]; };
union Pack4 { uint2 u2; bf16 h[4]; };
union PK2 { unsigned u; bf16 h[2]; };
union BP8 { uint4 u; bf16x8 v; };

#define QSCALE 0.18033688011112042f   // log2(e)/sqrt(64)

__device__ __forceinline__ void async16(const bf16* g, bf16* l) {
    __builtin_amdgcn_global_load_lds((const __attribute__((address_space(1))) void*)g,
                                     (__attribute__((address_space(3))) void*)l, 16, 0, 0);
}

// split-K item tables: 40 items per (b,h), ordered heaviest-first
__device__ const int QT_OF[40] = {15,15,15,15,14,14,14,14,13,13,13,13,12,12,12,12,
                                  11,11,11,10,10,10,9,9,9,8,8,8,7,7,6,6,5,5,4,4,3,2,1,0};
__device__ const int CK_OF[40] = {0,1,2,3,0,1,2,3,0,1,2,3,0,1,2,3,
                                  0,1,2,0,1,2,0,1,2,0,1,2,0,1,0,1,0,1,0,1,0,0,0,0};
__device__ const int BASE_OF[16] = {39,38,37,36,34,32,30,28,25,22,19,16,12,8,4,0};

// ---------------- prep: csum zero + fp32->bf16 convert + 3 weight transposes ----------------
__global__ void prep(const float* __restrict__ hs, bf16* __restrict__ hsb,
                     const float* __restrict__ qkw, const float* __restrict__ vw,
                     const float* __restrict__ pw, bf16* __restrict__ qkvT,
                     bf16* __restrict__ pwT, float* __restrict__ csum,
                     const float* __restrict__ vrg, const float* __restrict__ vsg,
                     const float* __restrict__ prg, const float* __restrict__ psg) {
    const int K = 1024;
    int bx = blockIdx.x;
    if (bx < 8) {
        float4* p = (float4*)csum + (bx * 256 + threadIdx.x) * 16;
        #pragma unroll
        for (int i = 0; i < 16; i++) p[i] = make_float4(0.f, 0.f, 0.f, 0.f);
        return;
    }
    if (bx < 4104) {
        int i = ((bx - 8) * 256 + threadIdx.x) * 4;
        float4 f = *(const float4*)(hs + i);
        hsb[i + 0] = (bf16)f.x; hsb[i + 1] = (bf16)f.y;
        hsb[i + 2] = (bf16)f.z; hsb[i + 3] = (bf16)f.w;
        return;
    }
    int r = bx - 4104;
    int z = r < 2048 ? 0 : (r < 3072 ? 1 : 2);
    int q = z == 0 ? r : (z == 1 ? r - 2048 : r - 3072);
    int ntiles = z == 0 ? 64 : 32;
    int N = z == 0 ? 2048 : 1024;
    const float* W = z == 0 ? qkw : (z == 1 ? vw : pw);
    bf16* WT = z == 0 ? qkvT : (z == 1 ? qkvT + (size_t)2 * 1024 * 1024 : pwT);
    float g0 = z == 0 ? 1.f : (z == 1 ? vrg[0] : prg[0]);
    float g1 = z == 0 ? 0.f : (z == 1 ? vsg[0] : psg[0]);

    __shared__ float tile[32][33];
    int n0 = (q % ntiles) * 32, k0 = (q / ntiles) * 32;
    int tx = threadIdx.x & 31, ty = threadIdx.x >> 5;
    #pragma unroll
    for (int rr = 0; rr < 32; rr += 8)
        tile[ty + rr][tx] = W[(size_t)(k0 + ty + rr) * N + n0 + tx];
    __syncthreads();
    #pragma unroll
    for (int rr = 0; rr < 32; rr += 8) {
        int n = n0 + ty + rr, k = k0 + tx;
        float v = g0 * tile[tx][ty + rr] + ((n == k) ? g1 : 0.f);
        if (z == 0 && n < 1024) v *= QSCALE;
        WT[(size_t)n * K + k] = (bf16)v;
    }
}

// ---------------- bf16 MFMA GEMM, XCD-swizzled 1D grid: C = A @ BT^T ----------------
template<int BN>
__global__ __launch_bounds__(256, 3)
void gemm_bt(const bf16* __restrict__ A, const bf16* __restrict__ BT,
             int M, int N, int K, void* __restrict__ Cout,
             bf16* __restrict__ C2T, float* __restrict__ csum,
             int mode, const float* __restrict__ aux) {
    __shared__ __align__(16) bf16 As[128][64];
    __shared__ __align__(16) bf16 Bs[BN][64];
    constexpr int JF = BN / 32;
    int bid = blockIdx.x;
    int g32 = bid & 31;
    int m0 = ((g32 & 7) * 4 + (g32 >> 3)) * 128;
    int n0 = (bid >> 5) * BN;
    int t = threadIdx.x, lane = t & 63, w = t >> 6;
    int wm = (w >> 1) * 64, wn = (w & 1) * (BN / 2);
    int lrow = lane & 15, lkg = lane >> 4;

    f32x4 acc[4][JF] = {};

    int gsw = ((lane & 7) ^ ((lane >> 3) & 7)) * 8;
    const bf16* Ab = A + (size_t)(m0 + w * 8 + (lane >> 3)) * K + gsw;
    const bf16* Bb = BT + (size_t)(n0 + w * 8 + (lane >> 3)) * K + gsw;

    for (int k0 = 0; k0 < K; k0 += 64) {
        #pragma unroll
        for (int p = 0; p < 4; p++)
            async16(Ab + (size_t)(p * 32) * K + k0, &As[p * 32 + w * 8][0]);
        #pragma unroll
        for (int p = 0; p < BN / 32; p++)
            async16(Bb + (size_t)(p * 32) * K + k0, &Bs[p * 32 + w * 8][0]);
        __syncthreads();
        #pragma unroll
        for (int ks = 0; ks < 2; ks++) {
            bf16x8 af[4], bfr[JF];
            int phys = (((4 * ks + lkg) ^ (lrow & 7)) << 3);
            #pragma unroll
            for (int i = 0; i < 4; i++) af[i] = *(const bf16x8*)&As[wm + i * 16 + lrow][phys];
            #pragma unroll
            for (int j = 0; j < JF; j++) bfr[j] = *(const bf16x8*)&Bs[wn + j * 16 + lrow][phys];
            #pragma unroll
            for (int i = 0; i < 4; i++)
                #pragma unroll
                for (int j = 0; j < JF; j++)
                    acc[i][j] = __builtin_amdgcn_mfma_f32_16x16x32_bf16(af[i], bfr[j], acc[i][j], 0, 0, 0);
        }
        __syncthreads();
    }

    int rgrp = (lane >> 4) * 4;
    #pragma unroll
    for (int i = 0; i < 4; i++) {
        #pragma unroll
        for (int j = 0; j < JF; j++) {
            int col = n0 + wn + j * 16 + lrow;
            int row0 = m0 + wm + i * 16 + rgrp;
            if (mode == 0) {
                if (col < 2048) {
                    float bb = aux[col];
                    if (col < 1024) bb *= QSCALE;
                    #pragma unroll
                    for (int reg = 0; reg < 4; reg++)
                        ((bf16*)Cout)[(size_t)(row0 + reg) * 2048 + col] = (bf16)(acc[i][j][reg] + bb);
                } else {
                    int c = col - 2048;
                    Pack4 p4;
                    #pragma unroll
                    for (int reg = 0; reg < 4; reg++) p4.h[reg] = (bf16)acc[i][j][reg];
                    *(uint2*)&C2T[(size_t)c * 4096 + row0] = p4.u2;
                }
            } else {
                #pragma unroll
                for (int reg = 0; reg < 4; reg++)
                    ((float*)Cout)[(size_t)(row0 + reg) * N + col] = acc[i][j][reg];
            }
        }
    }

    if (mode == 0 && n0 >= 2048) {
        int chunkb = (m0 + wm) >> 5;
        #pragma unroll
        for (int j = 0; j < JF; j++) {
            float s0 = 0.f, s1 = 0.f;
            #pragma unroll
            for (int reg = 0; reg < 4; reg++) {
                s0 += acc[0][j][reg] + acc[1][j][reg];
                s1 += acc[2][j][reg] + acc[3][j][reg];
            }
            s0 += __shfl_xor(s0, 16, 64); s0 += __shfl_xor(s0, 32, 64);
            s1 += __shfl_xor(s1, 16, 64); s1 += __shfl_xor(s1, 32, 64);
            if (lkg == 0) {
                int col = n0 - 2048 + wn + j * 16 + lrow;
                atomicAdd(&csum[(size_t)col * 128 + chunkb], s0);
                atomicAdd(&csum[(size_t)col * 128 + chunkb + 1], s1);
            }
        }
    }
}

// ---------------- flash split-K: Ps eliminated via cross-lane shuffles; 32 KB LDS, 5 blk/CU ----------------
__global__ __launch_bounds__(256, 5)
void flash_split(const bf16* __restrict__ qk, const bf16* __restrict__ vT,
                 bf16* __restrict__ Opart, float* __restrict__ lbuf,
                 int S, int E, int H) {
    // smem[0..8191]   = Ks[2][64][64]  (swizzled DMA)
    // smem[8192..16383] = Vt[2][64][64] (swizzled DMA)
    // epilogue: reinterpreted as per-wave [32][72] scratch
    __shared__ __align__(16) bf16 smem[16384];

    int item = blockIdx.x, bh = blockIdx.y;
    int qt = QT_OF[item], ck = CK_OF[item];
    int b = bh >> 4, h = bh & 15;
    int q0 = qt * 128;
    int ktstart = ck * 8;
    int nloc = min(8, 2 * (qt + 1) - ktstart);
    int t = threadIdx.x, lane = t & 63, w = t >> 6;
    int lrow = lane & 15, lkg = lane >> 4;
    const int ld = 2 * E;

    const bf16* Qg  = qk + (size_t)(b * S + q0) * ld + h * 64;
    const bf16* Kg0 = qk + (size_t)(b * S) * ld + E + h * 64;
    const bf16* Vg0 = vT + (size_t)(h * 64) * 4096 + b * 2048;

    bf16x8 qf[2][2];
    #pragma unroll
    for (int qg = 0; qg < 2; qg++)
        #pragma unroll
        for (int ks = 0; ks < 2; ks++)
            qf[qg][ks] = *(const bf16x8*)&Qg[(size_t)(32 * w + 16 * qg + lrow) * ld + ks * 32 + lkg * 8];

    f32x4 oacc[4][2] = {};
    float lrun[2] = {0.f, 0.f};

    auto stage = [&](int buf, int kt) {
        int k0 = kt * 64;
        int g = (lane & 7) ^ ((lane >> 3) & 7);
        #pragma unroll
        for (int p = 0; p < 2; p++) {
            int row = w * 8 + p * 32 + (lane >> 3);
            async16(Kg0 + (size_t)(k0 + row) * ld + g * 8, &smem[buf * 4096 + row * 64 + (lane & 7) * 8]);
            async16(Vg0 + (size_t)row * 4096 + k0 + g * 8, &smem[8192 + buf * 4096 + row * 64 + (lane & 7) * 8]);
        }
    };

    stage(0, ktstart);
    for (int kl = 0; kl < nloc; kl++) {
        int buf = kl & 1;
        int k0 = (ktstart + kl) * 64;
        __syncthreads();
        if (kl + 1 < nloc) stage(1 - buf, ktstart + kl + 1);

        bool skip0 = (k0 > q0 + 32 * w + 15);
        bool skip1 = (k0 > q0 + 32 * w + 31);
        if (skip0 && skip1) continue;

        f32x4 sacc[2][4] = {};
        #pragma unroll
        for (int ks = 0; ks < 2; ks++) {
            bf16x8 ak[4];
            int phys = (((4 * ks + lkg) ^ (lrow & 7)) << 3);
            #pragma unroll
            for (int kf = 0; kf < 4; kf++)
                ak[kf] = *(const bf16x8*)&smem[buf * 4096 + (16 * kf + lrow) * 64 + phys];
            #pragma unroll
            for (int kf = 0; kf < 4; kf++)
                sacc[0][kf] = __builtin_amdgcn_mfma_f32_16x16x32_bf16(ak[kf], qf[0][ks], sacc[0][kf], 0, 0, 0);
            if (!skip1)
                #pragma unroll
                for (int kf = 0; kf < 4; kf++)
                    sacc[1][kf] = __builtin_amdgcn_mfma_f32_16x16x32_bf16(ak[kf], qf[1][ks], sacc[1][kf], 0, 0, 0);
        }

        // fixed-base softmax -> packed bf16 pairs in registers (no LDS)
        unsigned plo[2][4], phi[2][4];
        #pragma unroll
        for (int qg = 0; qg < 2; qg++) {
            if ((qg == 0 && skip0) || (qg == 1 && skip1)) continue;
            int kmin = q0 + 32 * w + 16 * qg;
            float rsum = 0.f;
            if (k0 + 63 <= kmin) {
                #pragma unroll
                for (int kf = 0; kf < 4; kf++) {
                    float p0 = exp2f(sacc[qg][kf][0]), p1 = exp2f(sacc[qg][kf][1]);
                    float p2 = exp2f(sacc[qg][kf][2]), p3 = exp2f(sacc[qg][kf][3]);
                    rsum += (p0 + p1) + (p2 + p3);
                    PK2 a; a.h[0] = (bf16)p0; a.h[1] = (bf16)p1; plo[qg][kf] = a.u;
                    PK2 c; c.h[0] = (bf16)p2; c.h[1] = (bf16)p3; phi[qg][kf] = c.u;
                }
            } else {
                int qrow = kmin + lrow;
                #pragma unroll
                for (int kf = 0; kf < 4; kf++) {
                    float pv[4];
                    #pragma unroll
                    for (int r = 0; r < 4; r++) {
                        float sv = sacc[qg][kf][r];
                        if (k0 + 16 * kf + 4 * lkg + r > qrow) sv = -1e30f;
                        pv[r] = exp2f(sv);
                        rsum += pv[r];
                    }
                    PK2 a; a.h[0] = (bf16)pv[0]; a.h[1] = (bf16)pv[1]; plo[qg][kf] = a.u;
                    PK2 c; c.h[0] = (bf16)pv[2]; c.h[1] = (bf16)pv[3]; phi[qg][kf] = c.u;
                }
            }
            lrun[qg] += rsum;
        }

        // O^T += V^T P^T ; P B-frags built by cross-lane shuffle (no LDS round trip)
        int srcA = 32 * (lkg & 1) + lrow;
        int srcB = srcA + 16;
        bool sel = (lkg & 2) != 0;
        #pragma unroll
        for (int ks = 0; ks < 2; ks++) {
            bf16x8 av[4];
            int phys = (((4 * ks + lkg) ^ (lrow & 7)) << 3);
            #pragma unroll
            for (int df = 0; df < 4; df++)
                av[df] = *(const bf16x8*)&smem[8192 + buf * 4096 + (16 * df + lrow) * 64 + phys];
            #pragma unroll
            for (int qg = 0; qg < 2; qg++) {
                if ((qg == 0 && skip0) || (qg == 1 && skip1)) continue;
                unsigned aL0 = __shfl((int)plo[qg][2 * ks], srcA, 64);
                unsigned aH0 = __shfl((int)phi[qg][2 * ks], srcA, 64);
                unsigned aL1 = __shfl((int)plo[qg][2 * ks + 1], srcA, 64);
                unsigned aH1 = __shfl((int)phi[qg][2 * ks + 1], srcA, 64);
                unsigned bL0 = __shfl((int)plo[qg][2 * ks], srcB, 64);
                unsigned bH0 = __shfl((int)phi[qg][2 * ks], srcB, 64);
                unsigned bL1 = __shfl((int)plo[qg][2 * ks + 1], srcB, 64);
                unsigned bH1 = __shfl((int)phi[qg][2 * ks + 1], srcB, 64);
                BP8 W;
                W.u.x = sel ? aL1 : aL0;
                W.u.y = sel ? aH1 : aH0;
                W.u.z = sel ? bL1 : bL0;
                W.u.w = sel ? bH1 : bH0;
                #pragma unroll
                for (int df = 0; df < 4; df++)
                    oacc[df][qg] = __builtin_amdgcn_mfma_f32_16x16x32_bf16(av[df], W.v, oacc[df][qg], 0, 0, 0);
            }
        }
    }

    // epilogue: reuse smem as per-wave [32][72] scratch for coalesced Opart store
    __syncthreads();
    bf16* Sc = smem + w * 32 * 72;
    size_t ibase = (size_t)(bh * 40 + item) * 128;
    #pragma unroll
    for (int qg = 0; qg < 2; qg++) {
        #pragma unroll
        for (int df = 0; df < 4; df++) {
            Pack4 p4;
            #pragma unroll
            for (int r = 0; r < 4; r++) p4.h[r] = (bf16)oacc[df][qg][r];
            *(uint2*)&Sc[(16 * qg + lrow) * 72 + 16 * df + 4 * lkg] = p4.u2;
        }
        float l = lrun[qg];
        l += __shfl_xor(l, 16, 64);
        l += __shfl_xor(l, 32, 64);
        if (lkg == 0) lbuf[ibase + w * 32 + qg * 16 + lrow] = l;
    }
    int r_l = lane >> 1, half = lane & 1;
    bf16* orow = Opart + (ibase + w * 32 + r_l) * 64 + 32 * half;
    #pragma unroll
    for (int c = 0; c < 4; c++)
        *(uint4*)&orow[8 * c] = *(const uint4*)&Sc[r_l * 72 + 32 * half + 8 * c];
}

// ---------------- fused merge + combine (vectorized csum scan, V from vT) ----------------
__global__ void merge_combine(const bf16* __restrict__ Opart, const float* __restrict__ lbuf,
                              const bf16* __restrict__ vT, const float* __restrict__ csum,
                              const float* __restrict__ gr, const float* __restrict__ gs,
                              const float* __restrict__ gc, bf16* __restrict__ ctx) {
    const int S = 2048, E = 1024;
    int qt = blockIdx.x, bh = blockIdx.y;
    int b = bh >> 4, h = bh & 15;
    int nc = (qt >> 2) + 1, base = BASE_OF[qt];
    int q0 = qt * 128;
    int t = threadIdx.x;

    __shared__ bf16 osm[128][66];

    {
        int r = t >> 1, dh = (t & 1) * 32;
        float L = 0.f;
        for (int c = 0; c < nc; c++)
            L += lbuf[(size_t)(bh * 40 + base + c) * 128 + r];
        float inv = 1.f / L;
        float o[32] = {};
        for (int c = 0; c < nc; c++) {
            const bf16* src = Opart + ((size_t)(bh * 40 + base + c) * 128 + r) * 64 + dh;
            #pragma unroll
            for (int g = 0; g < 4; g++) {
                U16x8 u; u.u = *(const uint4*)&src[g * 8];
                #pragma unroll
                for (int j = 0; j < 8; j++) o[g * 8 + j] += (float)u.h[j];
            }
        }
        #pragma unroll
        for (int j = 0; j < 32; j++) osm[r][dh + j] = (bf16)(o[j] * inv);
    }
    __syncthreads();

    {
        int c = t & 63, sc = t >> 6;
        int col = h * 64 + c;
        int row0 = q0 + sc * 32;
        float grh = gr[h], gsh = gs[h], gch = gc[h];
        int cend = qt * 4 + sc;
        const float4* cs4 = (const float4*)(csum + (size_t)col * 128 + b * 64);
        float run = 0.f;
        #pragma unroll
        for (int g = 0; g < 16; g++) {
            float4 f = cs4[g];
            int j = g * 4;
            run += (j + 0 < cend ? f.x : 0.f) + (j + 1 < cend ? f.y : 0.f)
                 + (j + 2 < cend ? f.z : 0.f) + (j + 3 < cend ? f.w : 0.f);
        }
        const bf16* vrow = vT + (size_t)col * 4096 + b * 2048 + row0;
        U16x8 vv[4];
        #pragma unroll
        for (int g = 0; g < 4; g++) vv[g].u = *(const uint4*)&vrow[g * 8];
        bf16* cp = ctx + ((size_t)(b * S + row0)) * E + col;
        #pragma unroll
        for (int i = 0; i < 32; i++) {
            float v = (float)vv[i >> 3].h[i & 7];
            run += v;
            float pm = run / (float)(row0 + i + 1);
            cp[(size_t)i * E] = (bf16)(grh * (float)osm[sc * 32 + i][c] + gsh * v - gch * pm);
        }
    }
}

extern "C" void kernel_launch(void* const* d_in, const int* in_sizes, int n_in,
                              void* d_out, int out_size, void* d_ws, size_t ws_size,
                              hipStream_t stream) {
    const float* hs  = (const float*)d_in[0];
    const float* qkw = (const float*)d_in[1];
    const float* qkb = (const float*)d_in[2];
    const float* vw  = (const float*)d_in[3];
    const float* vrg = (const float*)d_in[4];
    const float* vsg = (const float*)d_in[5];
    const float* pw  = (const float*)d_in[6];
    const float* prg = (const float*)d_in[7];
    const float* psg = (const float*)d_in[8];
    const float* amr = (const float*)d_in[9];
    const float* ams = (const float*)d_in[10];
    const float* amc = (const float*)d_in[11];
    float* out = (float*)d_out;

    const int B = 2, S = 2048, E = 1024, H = 16, M = B * S;
    char* ws = (char*)d_ws;
    size_t off = 0;
    auto alloc = [&](size_t bytes) { void* p = ws + off; off += (bytes + 255) & ~255ull; return p; };
    bf16* hsb   = (bf16*)alloc((size_t)M * E * 2);
    bf16* qkvT  = (bf16*)alloc((size_t)3 * E * E * 2);
    bf16* pwT   = (bf16*)alloc((size_t)E * E * 2);
    bf16* qko   = (bf16*)alloc((size_t)M * 2 * E * 2);
    bf16* vT    = (bf16*)alloc((size_t)E * M * 2);
    float* csum = (float*)alloc((size_t)E * 128 * 4);
    bf16* ctxb  = (bf16*)alloc((size_t)M * E * 2);
    bf16* Opart = (bf16*)alloc((size_t)32 * 40 * 128 * 64 * 2);
    float* lbuf = (float*)alloc((size_t)32 * 40 * 128 * 4);

    prep<<<8200, 256, 0, stream>>>(hs, hsb, qkw, vw, pw, qkvT, pwT, csum, vrg, vsg, prg, psg);

    gemm_bt<128><<<32 * (3 * E / 128), 256, 0, stream>>>(
        hsb, qkvT, M, 3 * E, E, qko, vT, csum, 0, qkb);

    flash_split<<<dim3(40, 32), 256, 0, stream>>>(qko, vT, Opart, lbuf, S, E, H);
    merge_combine<<<dim3(16, 32), 256, 0, stream>>>(Opart, lbuf, vT, csum, amr, ams, amc, ctxb);

    gemm_bt<64><<<32 * (E / 64), 256, 0, stream>>>(
        ctxb, pwT, M, E, E, out, nullptr, nullptr, 2, nullptr);
}